// Round 4
// baseline (146.226 us; speedup 1.0000x reference)
//
#include <hip/hip_runtime.h>

#define BB 2
#define LL 4096
#define SS 4096
#define HH 8
#define DD 64
#define UU 45
#define SCALE 0.125f

// ---------------------------------------------------------------------------
// K1: M[bh*L + l] = max_u(dot) - sum_u(dot)/S   over 45 sampled keys.
// Re-tiled for head reuse: block = (b, 2 l-values) x all 8 heads.
// tid = (li*8 + h)*16 + sub. idx is shared across (b,h), so per u each
// 128-thread half-block reads ONE contiguous 2KB K row K[b][s][*][*]
// (float4 per lane, perfectly coalesced) serving all 8 heads at once.
// ---------------------------------------------------------------------------
__global__ __launch_bounds__(256) void k_compute_M(
    const float* __restrict__ q, const float* __restrict__ k,
    const int* __restrict__ idx, float* __restrict__ M) {
  __shared__ int sidx[2 * UU];
  int tid = threadIdx.x;
  int b  = blockIdx.x >> 11;            // 2048 blocks per batch
  int l0 = (blockIdx.x & 2047) << 1;    // 2 l per block
  for (int i = tid; i < 2 * UU; i += 256) sidx[i] = idx[(long)l0 * UU + i];
  __syncthreads();

  int slot = tid >> 4;                  // 0..15
  int li   = slot >> 3;                 // which l
  int h    = slot & 7;                  // head
  int sub  = tid & 15;                  // d-quarter (float4)
  int l = l0 + li;

  const float4* qp = (const float4*)(q + (((long)b * LL + l) * HH + h) * DD);
  float4 qq = qp[sub];
  const float* kb = k + (long)b * SS * HH * DD + h * DD;

  float mx = -INFINITY, sm = 0.f;
  #pragma unroll 9
  for (int u = 0; u < UU; ++u) {
    int s = sidx[li * UU + u];          // same s for all lanes of the slot
    float4 kk4 = ((const float4*)(kb + (long)s * (HH * DD)))[sub];
    float p = qq.x * kk4.x + qq.y * kk4.y + qq.z * kk4.z + qq.w * kk4.w;
    #pragma unroll
    for (int off = 8; off; off >>= 1) p += __shfl_xor(p, off, 16);
    mx = fmaxf(mx, p);
    sm += p;
  }
  if (sub == 0) M[((long)(b * HH + h)) * LL + l] = mx - sm * (1.0f / SS);
}

// ---------------------------------------------------------------------------
// K2: top-45 per (b,h) via 4-pass radix-select on orderable uint32 keys,
// then rank-based emit. Matches jax.lax.top_k: value desc, ties -> lowest
// index. One block (256 thr) per bh.
// ---------------------------------------------------------------------------
__global__ __launch_bounds__(256) void k_topk(
    const float* __restrict__ M, int* __restrict__ Mtop) {
  __shared__ unsigned keys[LL];        // 16 KB orderable keys
  __shared__ int hist[256];
  __shared__ int wsum[4];
  __shared__ int sh_bin, sh_gtwin;
  __shared__ int ccount, ecount;
  __shared__ unsigned cand_key[64];
  __shared__ int cand_idx[64];
  __shared__ int elist[LL];            // ==T indices (worst-case capacity)

  int bh = blockIdx.x, tid = threadIdx.x;
  int lane = tid & 63, w = tid >> 6;
  const float* m = M + (long)bh * LL;
  for (int i = tid; i < LL; i += 256) {
    union { float f; unsigned u; } cv; cv.f = m[i];
    keys[i] = (cv.u & 0x80000000u) ? ~cv.u : (cv.u | 0x80000000u);
  }
  if (tid == 0) { ccount = 0; ecount = 0; }
  __syncthreads();

  unsigned prefix = 0, pmask = 0;
  int need = UU, above = 0;

  for (int shift = 24; shift >= 0; shift -= 8) {
    hist[tid] = 0;
    __syncthreads();
    #pragma unroll
    for (int j = 0; j < 16; ++j) {
      unsigned kk = keys[tid + (j << 8)];
      if ((kk & pmask) == prefix) atomicAdd(&hist[(kk >> shift) & 255], 1);
    }
    __syncthreads();
    int v = hist[tid];
    int sfx = v;
    #pragma unroll
    for (int st = 1; st < 64; st <<= 1) {
      int o = __shfl_down(sfx, st, 64);
      if (lane + st < 64) sfx += o;
    }
    if (lane == 0) wsum[w] = sfx;
    __syncthreads();
    for (int t = w + 1; t < 4; ++t) sfx += wsum[t];
    int gt = sfx - v;
    if (gt < need && sfx >= need) {
      sh_bin = tid;
      sh_gtwin = gt;
    }
    __syncthreads();
    prefix |= ((unsigned)sh_bin << shift);
    pmask  |= (255u << shift);
    need  -= sh_gtwin;
    above += sh_gtwin;
    __syncthreads();
  }
  unsigned T = prefix;

  #pragma unroll
  for (int j = 0; j < 16; ++j) {
    int i = tid + (j << 8);
    unsigned kk = keys[i];
    if (kk > T)      { int p = atomicAdd(&ccount, 1); cand_key[p] = kk; cand_idx[p] = i; }
    else if (kk == T){ int p = atomicAdd(&ecount, 1); elist[p] = i; }
  }
  __syncthreads();
  int nc = ccount, ne = ecount;
  for (int t = tid; t < nc; t += 256) {
    unsigned kk = cand_key[t]; int ii = cand_idx[t]; int r = 0;
    for (int j = 0; j < nc; ++j)
      r += (cand_key[j] > kk) || (cand_key[j] == kk && cand_idx[j] < ii);
    Mtop[bh * UU + r] = ii;
  }
  for (int t = tid; t < ne; t += 256) {
    int ii = elist[t]; int r = 0;
    for (int j = 0; j < ne; ++j) r += (elist[j] < ii);
    if (r < need) Mtop[bh * UU + above + r] = ii;
  }
}

// ---------------------------------------------------------------------------
// K3: scores[u][s] = (Qr[u] . K[s]) * SCALE for one bh, 256 s per block.
// ---------------------------------------------------------------------------
__global__ __launch_bounds__(256) void k_scores(
    const float* __restrict__ q, const float* __restrict__ k,
    const int* __restrict__ Mtop, float* __restrict__ attn) {
  __shared__ float qr[UU * DD];
  int bh = blockIdx.y;
  int b = bh >> 3, h = bh & 7;
  for (int i = threadIdx.x; i < UU * DD; i += 256) {
    int u = i >> 6, d = i & 63;
    int l = Mtop[bh * UU + u];
    qr[i] = q[(((long)b * LL + l) * HH + h) * DD + d];
  }
  __syncthreads();
  int s = blockIdx.x * 256 + threadIdx.x;
  float4 kr[16];
  const float4* kp = (const float4*)(k + (((long)b * SS + s) * HH + h) * DD);
  #pragma unroll
  for (int j = 0; j < 16; ++j) kr[j] = kp[j];
  for (int u = 0; u < UU; ++u) {
    const float4* qp = (const float4*)(qr + u * DD);
    float acc = 0.f;
    #pragma unroll
    for (int j = 0; j < 16; ++j) {
      float4 qq = qp[j];
      acc += qq.x * kr[j].x + qq.y * kr[j].y + qq.z * kr[j].z + qq.w * kr[j].w;
    }
    attn[((long)bh * UU + u) * SS + s] = acc * SCALE;
  }
}

// ---------------------------------------------------------------------------
// K4: row softmax over S=4096, one block per row (720 rows), in place.
// ---------------------------------------------------------------------------
__global__ __launch_bounds__(256) void k_softmax(float* __restrict__ attn) {
  __shared__ float red[256];
  long row = blockIdx.x;
  float* a = attn + row * SS;
  float v[16];
  float mx = -INFINITY;
  #pragma unroll
  for (int j = 0; j < 16; ++j) {
    v[j] = a[j * 256 + threadIdx.x];
    mx = fmaxf(mx, v[j]);
  }
  red[threadIdx.x] = mx;
  __syncthreads();
  for (int st = 128; st; st >>= 1) {
    if (threadIdx.x < st) red[threadIdx.x] = fmaxf(red[threadIdx.x], red[threadIdx.x + st]);
    __syncthreads();
  }
  mx = red[0];
  __syncthreads();
  float sm = 0.f;
  #pragma unroll
  for (int j = 0; j < 16; ++j) {
    v[j] = __expf(v[j] - mx);
    sm += v[j];
  }
  red[threadIdx.x] = sm;
  __syncthreads();
  for (int st = 128; st; st >>= 1) {
    if (threadIdx.x < st) red[threadIdx.x] += red[threadIdx.x + st];
    __syncthreads();
  }
  float inv = 1.0f / red[0];
  #pragma unroll
  for (int j = 0; j < 16; ++j) a[j * 256 + threadIdx.x] = v[j] * inv;
}

// ---------------------------------------------------------------------------
// K5a: chunked context partials. grid = (nch, B*H); block = 256 (4 waves).
// All 45 u-accumulators in registers (lane = d); attn chunk staged transposed
// in LDS (row stride 52). V and attn each read once from HBM. Partials -> ws.
// ---------------------------------------------------------------------------
__global__ __launch_bounds__(256) void k_context_part(
    const float* __restrict__ attn, const float* __restrict__ v,
    float* __restrict__ part, int nch) {
  __shared__ float smem[4 * UU * DD];   // 11520 floats; staging uses 128*52
  int ch = blockIdx.x, bh = blockIdx.y;
  int b = bh >> 3, h = bh & 7;
  int tid = threadIdx.x;
  int ln = tid & 63, w = tid >> 6;
  int chunk = SS / nch;
  int s0 = ch * chunk;
  int nsub = chunk >> 7;                // 128-s sub-tiles

  float acc[UU];
  #pragma unroll
  for (int u = 0; u < UU; ++u) acc[u] = 0.f;

  const float* vb = v + (long)b * SS * HH * DD + h * DD + ln;

  for (int sub = 0; sub < nsub; ++sub) {
    int sb = s0 + (sub << 7);
    __syncthreads();
    for (int i = tid; i < UU * 128; i += 256) {
      int u = i >> 7, si = i & 127;
      smem[si * 52 + u] = attn[((long)bh * UU + u) * SS + sb + si];
    }
    __syncthreads();
    #pragma unroll 2
    for (int j = 0; j < 32; ++j) {
      int sl = (j << 2) + w;
      float vd = vb[(long)(sb + sl) * (HH * DD)];
      const float* ar = smem + sl * 52;
      #pragma unroll
      for (int g = 0; g < 11; ++g) {
        float4 aa = *(const float4*)(ar + g * 4);
        acc[g * 4 + 0] += aa.x * vd;
        acc[g * 4 + 1] += aa.y * vd;
        acc[g * 4 + 2] += aa.z * vd;
        acc[g * 4 + 3] += aa.w * vd;
      }
      acc[44] += ar[44] * vd;
    }
  }

  __syncthreads();
  #pragma unroll
  for (int u = 0; u < UU; ++u) smem[(w * UU + u) * DD + ln] = acc[u];
  __syncthreads();
  long base = ((long)bh * nch + ch) * (UU * DD);
  for (int i = tid; i < UU * DD; i += 256)
    part[base + i] = smem[i] + smem[UU * DD + i] + smem[2 * UU * DD + i] + smem[3 * UU * DD + i];
}

// K5b: sum partials over chunks. 46080 outputs.
__global__ __launch_bounds__(256) void k_context_reduce(
    const float* __restrict__ part, float* __restrict__ ctx, int nch) {
  int g = blockIdx.x * 256 + threadIdx.x;     // < B*H*U*D = 46080
  int bh = g / (UU * DD);
  int r  = g - bh * (UU * DD);
  float s = 0.f;
  for (int ch = 0; ch < nch; ++ch)
    s += part[((long)bh * nch + ch) * (UU * DD) + r];
  ctx[g] = s;
}

// Fallback (row-per-block context) if d_ws is too small.
__global__ __launch_bounds__(256) void k_context_fb(
    const float* __restrict__ attn, const float* __restrict__ v,
    float* __restrict__ ctx) {
  __shared__ float red[4][DD];
  int row = blockIdx.x;
  int bh = row / UU;
  int b = bh >> 3, h = bh & 7;
  int lane = threadIdx.x & 63;
  int grp = threadIdx.x >> 6;
  const float* a = attn + (long)row * SS;
  float acc = 0.f;
  for (int s = grp; s < SS; s += 4)
    acc += a[s] * v[(((long)b * SS + s) * HH + h) * DD + lane];
  red[grp][lane] = acc;
  __syncthreads();
  if (grp == 0)
    ctx[(long)row * DD + lane] = red[0][lane] + red[1][lane] + red[2][lane] + red[3][lane];
}

extern "C" void kernel_launch(void* const* d_in, const int* in_sizes, int n_in,
                              void* d_out, int out_size, void* d_ws, size_t ws_size,
                              hipStream_t stream) {
  const float* q   = (const float*)d_in[0];
  const float* k   = (const float*)d_in[1];
  const float* v   = (const float*)d_in[2];
  const int*   idx = (const int*)d_in[3];

  float* out  = (float*)d_out;
  float* ctx  = out;                           // B*H*U*D = 46080 floats
  float* attn = out + (long)BB * HH * UU * DD; // B*H*U*S floats

  // Scratch overlays on d_out (safe via stream ordering):
  //  - M lives at start of attn region (consumed by K2 before K3 overwrites)
  //  - Mtop lives at start of ctx region (consumed by K3 before K5 overwrites)
  float* M    = attn;
  int*   Mtop = (int*)ctx;

  k_compute_M<<<BB * LL / 2, 256, 0, stream>>>(q, k, idx, M);
  k_topk<<<BB * HH, 256, 0, stream>>>(M, Mtop);
  k_scores<<<dim3(SS / 256, BB * HH), 256, 0, stream>>>(q, k, Mtop, attn);
  k_softmax<<<BB * HH * UU, 256, 0, stream>>>(attn);

  size_t per_chunk = (size_t)BB * HH * UU * DD * sizeof(float);  // 184320 B
  int nch = 0;
  for (int c = 32; c >= 1; c >>= 1)
    if (ws_size >= per_chunk * (size_t)c) { nch = c; break; }
  if (nch) {
    k_context_part<<<dim3(nch, BB * HH), 256, 0, stream>>>(attn, v, (float*)d_ws, nch);
    k_context_reduce<<<(BB * HH * UU * DD) / 256, 256, 0, stream>>>((const float*)d_ws, ctx, nch);
  } else {
    k_context_fb<<<BB * HH * UU, 256, 0, stream>>>(attn, v, ctx);
  }
}

// Round 5
// 122.685 us; speedup vs baseline: 1.1919x; 1.1919x over previous
//
#include <hip/hip_runtime.h>

#define BB 2
#define LL 4096
#define SS 4096
#define HH 8
#define DD 64
#define UU 45
#define SCALE 0.125f

// ---------------------------------------------------------------------------
// K1: M[bh*L + l] = max_u(dot) - sum_u(dot)/S   over 45 sampled keys.
// Round-3 structure (16-lane slots, per-head 256B float4 gather, width-16
// shuffle reduce) + XCD pinning: bh lives in the low 4 bits of blockIdx, so
// all blocks of head-slice bh land on XCD bh%8 (blockIdx%8 = XCD). Per-XCD
// K working set = 2 head-slices = 2MB -> fits 4MB L2; the 755MB logical
// gather is L2-served, HBM sees only compulsory traffic.
// ---------------------------------------------------------------------------
__global__ __launch_bounds__(256) void k_compute_M(
    const float* __restrict__ q, const float* __restrict__ k,
    const int* __restrict__ idx, float* __restrict__ M) {
  __shared__ int sidx[16 * UU];
  int tid = threadIdx.x;
  int bh = blockIdx.x & 15;            // low bits -> XCD pin (bh%8)
  int l0 = (blockIdx.x >> 4) << 4;     // 16 l per block
  for (int i = tid; i < 16 * UU; i += 256) sidx[i] = idx[(long)l0 * UU + i];
  __syncthreads();

  int slot = tid >> 4;    // which l within block
  int sub  = tid & 15;    // d-quarter
  int l = l0 + slot;
  int b = bh >> 3, h = bh & 7;

  const float4* qp = (const float4*)(q + (((long)b * LL + l) * HH + h) * DD);
  float4 qq = qp[sub];
  const float* kb = k + (long)b * SS * HH * DD + h * DD;

  float mx = -INFINITY, sm = 0.f;
  #pragma unroll 5
  for (int u = 0; u < UU; ++u) {
    int s = sidx[slot * UU + u];
    float4 kk4 = ((const float4*)(kb + (long)s * (HH * DD)))[sub];
    float p = qq.x * kk4.x + qq.y * kk4.y + qq.z * kk4.z + qq.w * kk4.w;
    #pragma unroll
    for (int off = 8; off; off >>= 1) p += __shfl_xor(p, off, 16);
    mx = fmaxf(mx, p);
    sm += p;
  }
  if (sub == 0) M[(long)bh * LL + l] = mx - sm * (1.0f / SS);
}

// ---------------------------------------------------------------------------
// K2: top-45 per (b,h) via 4-pass radix-select on orderable uint32 keys,
// then rank-based emit. Matches jax.lax.top_k: value desc, ties -> lowest
// index. One block (256 thr) per bh.
// ---------------------------------------------------------------------------
__global__ __launch_bounds__(256) void k_topk(
    const float* __restrict__ M, int* __restrict__ Mtop) {
  __shared__ unsigned keys[LL];        // 16 KB orderable keys
  __shared__ int hist[256];
  __shared__ int wsum[4];
  __shared__ int sh_bin, sh_gtwin;
  __shared__ int ccount, ecount;
  __shared__ unsigned cand_key[64];
  __shared__ int cand_idx[64];
  __shared__ int elist[LL];            // ==T indices (worst-case capacity)

  int bh = blockIdx.x, tid = threadIdx.x;
  int lane = tid & 63, w = tid >> 6;
  const float* m = M + (long)bh * LL;
  for (int i = tid; i < LL; i += 256) {
    union { float f; unsigned u; } cv; cv.f = m[i];
    keys[i] = (cv.u & 0x80000000u) ? ~cv.u : (cv.u | 0x80000000u);
  }
  if (tid == 0) { ccount = 0; ecount = 0; }
  __syncthreads();

  unsigned prefix = 0, pmask = 0;
  int need = UU, above = 0;

  for (int shift = 24; shift >= 0; shift -= 8) {
    hist[tid] = 0;
    __syncthreads();
    #pragma unroll
    for (int j = 0; j < 16; ++j) {
      unsigned kk = keys[tid + (j << 8)];
      if ((kk & pmask) == prefix) atomicAdd(&hist[(kk >> shift) & 255], 1);
    }
    __syncthreads();
    int v = hist[tid];
    int sfx = v;
    #pragma unroll
    for (int st = 1; st < 64; st <<= 1) {
      int o = __shfl_down(sfx, st, 64);
      if (lane + st < 64) sfx += o;
    }
    if (lane == 0) wsum[w] = sfx;
    __syncthreads();
    for (int t = w + 1; t < 4; ++t) sfx += wsum[t];
    int gt = sfx - v;
    if (gt < need && sfx >= need) {
      sh_bin = tid;
      sh_gtwin = gt;
    }
    __syncthreads();
    prefix |= ((unsigned)sh_bin << shift);
    pmask  |= (255u << shift);
    need  -= sh_gtwin;
    above += sh_gtwin;
    __syncthreads();
  }
  unsigned T = prefix;

  #pragma unroll
  for (int j = 0; j < 16; ++j) {
    int i = tid + (j << 8);
    unsigned kk = keys[i];
    if (kk > T)      { int p = atomicAdd(&ccount, 1); cand_key[p] = kk; cand_idx[p] = i; }
    else if (kk == T){ int p = atomicAdd(&ecount, 1); elist[p] = i; }
  }
  __syncthreads();
  int nc = ccount, ne = ecount;
  for (int t = tid; t < nc; t += 256) {
    unsigned kk = cand_key[t]; int ii = cand_idx[t]; int r = 0;
    for (int j = 0; j < nc; ++j)
      r += (cand_key[j] > kk) || (cand_key[j] == kk && cand_idx[j] < ii);
    Mtop[bh * UU + r] = ii;
  }
  for (int t = tid; t < ne; t += 256) {
    int ii = elist[t]; int r = 0;
    for (int j = 0; j < ne; ++j) r += (elist[j] < ii);
    if (r < need) Mtop[bh * UU + above + r] = ii;
  }
}

// ---------------------------------------------------------------------------
// K3: scores[u][s] = (Qr[u] . K[s]) * SCALE for one bh, 256 s per block.
// ---------------------------------------------------------------------------
__global__ __launch_bounds__(256) void k_scores(
    const float* __restrict__ q, const float* __restrict__ k,
    const int* __restrict__ Mtop, float* __restrict__ attn) {
  __shared__ float qr[UU * DD];
  int bh = blockIdx.y;
  int b = bh >> 3, h = bh & 7;
  for (int i = threadIdx.x; i < UU * DD; i += 256) {
    int u = i >> 6, d = i & 63;
    int l = Mtop[bh * UU + u];
    qr[i] = q[(((long)b * LL + l) * HH + h) * DD + d];
  }
  __syncthreads();
  int s = blockIdx.x * 256 + threadIdx.x;
  float4 kr[16];
  const float4* kp = (const float4*)(k + (((long)b * SS + s) * HH + h) * DD);
  #pragma unroll
  for (int j = 0; j < 16; ++j) kr[j] = kp[j];
  for (int u = 0; u < UU; ++u) {
    const float4* qp = (const float4*)(qr + u * DD);
    float acc = 0.f;
    #pragma unroll
    for (int j = 0; j < 16; ++j) {
      float4 qq = qp[j];
      acc += qq.x * kr[j].x + qq.y * kr[j].y + qq.z * kr[j].z + qq.w * kr[j].w;
    }
    attn[((long)bh * UU + u) * SS + s] = acc * SCALE;
  }
}

// ---------------------------------------------------------------------------
// K4: row softmax over S=4096, one block per row (720 rows), in place.
// ---------------------------------------------------------------------------
__global__ __launch_bounds__(256) void k_softmax(float* __restrict__ attn) {
  __shared__ float red[256];
  long row = blockIdx.x;
  float* a = attn + row * SS;
  float v[16];
  float mx = -INFINITY;
  #pragma unroll
  for (int j = 0; j < 16; ++j) {
    v[j] = a[j * 256 + threadIdx.x];
    mx = fmaxf(mx, v[j]);
  }
  red[threadIdx.x] = mx;
  __syncthreads();
  for (int st = 128; st; st >>= 1) {
    if (threadIdx.x < st) red[threadIdx.x] = fmaxf(red[threadIdx.x], red[threadIdx.x + st]);
    __syncthreads();
  }
  mx = red[0];
  __syncthreads();
  float sm = 0.f;
  #pragma unroll
  for (int j = 0; j < 16; ++j) {
    v[j] = __expf(v[j] - mx);
    sm += v[j];
  }
  red[threadIdx.x] = sm;
  __syncthreads();
  for (int st = 128; st; st >>= 1) {
    if (threadIdx.x < st) red[threadIdx.x] += red[threadIdx.x + st];
    __syncthreads();
  }
  float inv = 1.0f / red[0];
  #pragma unroll
  for (int j = 0; j < 16; ++j) a[j * 256 + threadIdx.x] = v[j] * inv;
}

// ---------------------------------------------------------------------------
// K5a: chunked context partials. grid = (nch, B*H); block = 256 (4 waves).
// All 45 u-accumulators in registers (lane = d); attn chunk staged transposed
// in LDS (row stride 52). V and attn each read once from HBM. Partials -> ws.
// ---------------------------------------------------------------------------
__global__ __launch_bounds__(256) void k_context_part(
    const float* __restrict__ attn, const float* __restrict__ v,
    float* __restrict__ part, int nch) {
  __shared__ float smem[4 * UU * DD];   // 11520 floats; staging uses 128*52
  int ch = blockIdx.x, bh = blockIdx.y;
  int b = bh >> 3, h = bh & 7;
  int tid = threadIdx.x;
  int ln = tid & 63, w = tid >> 6;
  int chunk = SS / nch;
  int s0 = ch * chunk;
  int nsub = chunk >> 7;                // 128-s sub-tiles

  float acc[UU];
  #pragma unroll
  for (int u = 0; u < UU; ++u) acc[u] = 0.f;

  const float* vb = v + (long)b * SS * HH * DD + h * DD + ln;

  for (int sub = 0; sub < nsub; ++sub) {
    int sb = s0 + (sub << 7);
    __syncthreads();
    for (int i = tid; i < UU * 128; i += 256) {
      int u = i >> 7, si = i & 127;
      smem[si * 52 + u] = attn[((long)bh * UU + u) * SS + sb + si];
    }
    __syncthreads();
    #pragma unroll 2
    for (int j = 0; j < 32; ++j) {
      int sl = (j << 2) + w;
      float vd = vb[(long)(sb + sl) * (HH * DD)];
      const float* ar = smem + sl * 52;
      #pragma unroll
      for (int g = 0; g < 11; ++g) {
        float4 aa = *(const float4*)(ar + g * 4);
        acc[g * 4 + 0] += aa.x * vd;
        acc[g * 4 + 1] += aa.y * vd;
        acc[g * 4 + 2] += aa.z * vd;
        acc[g * 4 + 3] += aa.w * vd;
      }
      acc[44] += ar[44] * vd;
    }
  }

  __syncthreads();
  #pragma unroll
  for (int u = 0; u < UU; ++u) smem[(w * UU + u) * DD + ln] = acc[u];
  __syncthreads();
  long base = ((long)bh * nch + ch) * (UU * DD);
  for (int i = tid; i < UU * DD; i += 256)
    part[base + i] = smem[i] + smem[UU * DD + i] + smem[2 * UU * DD + i] + smem[3 * UU * DD + i];
}

// K5b: sum partials over chunks. 46080 outputs.
__global__ __launch_bounds__(256) void k_context_reduce(
    const float* __restrict__ part, float* __restrict__ ctx, int nch) {
  int g = blockIdx.x * 256 + threadIdx.x;     // < B*H*U*D = 46080
  int bh = g / (UU * DD);
  int r  = g - bh * (UU * DD);
  float s = 0.f;
  for (int ch = 0; ch < nch; ++ch)
    s += part[((long)bh * nch + ch) * (UU * DD) + r];
  ctx[g] = s;
}

// Fallback (row-per-block context) if d_ws is too small.
__global__ __launch_bounds__(256) void k_context_fb(
    const float* __restrict__ attn, const float* __restrict__ v,
    float* __restrict__ ctx) {
  __shared__ float red[4][DD];
  int row = blockIdx.x;
  int bh = row / UU;
  int b = bh >> 3, h = bh & 7;
  int lane = threadIdx.x & 63;
  int grp = threadIdx.x >> 6;
  const float* a = attn + (long)row * SS;
  float acc = 0.f;
  for (int s = grp; s < SS; s += 4)
    acc += a[s] * v[(((long)b * SS + s) * HH + h) * DD + lane];
  red[grp][lane] = acc;
  __syncthreads();
  if (grp == 0)
    ctx[(long)row * DD + lane] = red[0][lane] + red[1][lane] + red[2][lane] + red[3][lane];
}

extern "C" void kernel_launch(void* const* d_in, const int* in_sizes, int n_in,
                              void* d_out, int out_size, void* d_ws, size_t ws_size,
                              hipStream_t stream) {
  const float* q   = (const float*)d_in[0];
  const float* k   = (const float*)d_in[1];
  const float* v   = (const float*)d_in[2];
  const int*   idx = (const int*)d_in[3];

  float* out  = (float*)d_out;
  float* ctx  = out;                           // B*H*U*D = 46080 floats
  float* attn = out + (long)BB * HH * UU * DD; // B*H*U*S floats

  // Scratch overlays on d_out (safe via stream ordering):
  //  - M lives at start of attn region (consumed by K2 before K3 overwrites)
  //  - Mtop lives at start of ctx region (consumed by K3 before K5 overwrites)
  float* M    = attn;
  int*   Mtop = (int*)ctx;

  k_compute_M<<<BB * HH * LL / 16, 256, 0, stream>>>(q, k, idx, M);
  k_topk<<<BB * HH, 256, 0, stream>>>(M, Mtop);
  k_scores<<<dim3(SS / 256, BB * HH), 256, 0, stream>>>(q, k, Mtop, attn);
  k_softmax<<<BB * HH * UU, 256, 0, stream>>>(attn);

  size_t per_chunk = (size_t)BB * HH * UU * DD * sizeof(float);  // 184320 B
  int nch = 0;
  for (int c = 32; c >= 1; c >>= 1)
    if (ws_size >= per_chunk * (size_t)c) { nch = c; break; }
  if (nch) {
    k_context_part<<<dim3(nch, BB * HH), 256, 0, stream>>>(attn, v, (float*)d_ws, nch);
    k_context_reduce<<<(BB * HH * UU * DD) / 256, 256, 0, stream>>>((const float*)d_ws, ctx, nch);
  } else {
    k_context_fb<<<BB * HH * UU, 256, 0, stream>>>(attn, v, ctx);
  }
}